// Round 1
// baseline (1019.981 us; speedup 1.0000x reference)
//
#include <hip/hip_runtime.h>

#define B_TOT 8192
#define T_OBS 128
#define T_FUT 64
#define T_ALL 192
#define DIN 5
#define HD 128
#define BT 16          // batch rows per block (one 16-row MFMA A-tile)
#define LDSTR 136      // LDS row stride in shorts (pad 8 to spread banks)

typedef __attribute__((ext_vector_type(8))) short short8;
typedef __attribute__((ext_vector_type(4))) float f32x4;

__device__ inline short f2bf(float f) {
    unsigned u = __float_as_uint(f);
    u += 0x7FFFu + ((u >> 16) & 1u);   // round-to-nearest-even
    return (short)(u >> 16);
}

__device__ inline float sigm(float x) {
    return __builtin_amdgcn_rcpf(1.f + __expf(-x));
}
__device__ inline float tanh_(float x) {
    return 1.f - 2.f * __builtin_amdgcn_rcpf(1.f + __expf(2.f * x));
}

__device__ inline f32x4 MFMA(short8 a, short8 b, f32x4 c) {
    return __builtin_amdgcn_mfma_f32_16x16x32_bf16(a, b, c, 0, 0, 0);
}

__device__ inline short8 load_w8(const float* p) {
    float4 a = *reinterpret_cast<const float4*>(p);
    float4 b = *reinterpret_cast<const float4*>(p + 4);
    short8 r;
    r[0] = f2bf(a.x); r[1] = f2bf(a.y); r[2] = f2bf(a.z); r[3] = f2bf(a.w);
    r[4] = f2bf(b.x); r[5] = f2bf(b.y); r[6] = f2bf(b.z); r[7] = f2bf(b.w);
    return r;
}
__device__ inline short8 load_w5(const float* p) {
    short8 r = (short8)0;
    r[0] = f2bf(p[0]); r[1] = f2bf(p[1]); r[2] = f2bf(p[2]);
    r[3] = f2bf(p[3]); r[4] = f2bf(p[4]);
    return r;
}

// 512 threads = 8 waves. Wave w owns gate-columns [16w, 16w+16) of each of
// r/z/n. Block owns 16 batch rows (one 16-row A-tile). Weights live in
// VGPRs: 15 short8 = 60 VGPRs/lane. BT=16 -> 512 blocks -> 2 blocks/CU:
// two independent recurrences per CU interleave their per-step latency
// chains (barrier, LDS round-trip, MFMA chain, transcendentals).
__global__ __launch_bounds__(512, 4)
void gru_tracemodel_kernel(const float* __restrict__ obs, const float* __restrict__ target,
                           const float* __restrict__ eWih, const float* __restrict__ eWhh,
                           const float* __restrict__ ebih, const float* __restrict__ ebhh,
                           const float* __restrict__ cWih, const float* __restrict__ cWhh,
                           const float* __restrict__ cbih, const float* __restrict__ cbhh,
                           const float* __restrict__ headW, const float* __restrict__ headb,
                           float* __restrict__ out)
{
    __shared__ __attribute__((aligned(16))) short Abuf[2][BT][LDSTR];

    const int tid   = threadIdx.x;
    const int wave  = tid >> 6;    // 0..7
    const int lane  = tid & 63;
    const int q     = lane >> 4;   // quad (A/B k-group, C/D row-group)
    const int c     = lane & 15;   // col-in-tile / A row
    const int b0    = blockIdx.x * BT;
    const int wbase = wave * 16;   // this wave's gate-column slice

    // h0 = 0
    for (int i = tid; i < 2 * BT * LDSTR; i += 512) ((short*)Abuf)[i] = 0;

    // ---- weight fragments (B-operand: lane holds W'[n][k = kt*32+q*8+j]) ----
    // kt 0..3: Whh K-tiles; kt 4: zero-padded Wih x-tile (only q==0 nonzero)
    short8 Wr[5], Wz[5], Wn[5];
    float  br, bz, bnh_, bni_;

    auto load_phase = [&](const float* Wih, const float* Whh,
                          const float* bih, const float* bhh) {
        const int nr = 0 * HD + wbase + c;
        const int nz = 1 * HD + wbase + c;
        const int nn = 2 * HD + wbase + c;
        #pragma unroll
        for (int kt = 0; kt < 4; ++kt) {
            Wr[kt] = load_w8(Whh + nr * HD + kt * 32 + q * 8);
            Wz[kt] = load_w8(Whh + nz * HD + kt * 32 + q * 8);
            Wn[kt] = load_w8(Whh + nn * HD + kt * 32 + q * 8);
        }
        Wr[4] = (q == 0) ? load_w5(Wih + nr * DIN) : (short8)0;
        Wz[4] = (q == 0) ? load_w5(Wih + nz * DIN) : (short8)0;
        Wn[4] = (q == 0) ? load_w5(Wih + nn * DIN) : (short8)0;
        br   = bih[nr] + bhh[nr];
        bz   = bih[nz] + bhh[nz];
        bnh_ = bhh[nn];
        bni_ = bih[nn];
    };
    load_phase(eWih, eWhh, ebih, ebhh);

    // head fragments (wave 0 only): B[k][d], d = c (<5), from headW[d][k]
    short8 Whd[4];
    float  hb = 0.f;
    if (wave == 0) {
        #pragma unroll
        for (int kt = 0; kt < 4; ++kt)
            Whd[kt] = (c < DIN) ? load_w8(headW + c * HD + kt * 32 + q * 8) : (short8)0;
        hb = (c < DIN) ? headb[c] : 0.f;
    }

    // fp32 carried h: hreg[r] = h[row q*4+r][wbase+c]
    float hreg[4] = {0.f, 0.f, 0.f, 0.f};

    const float* obsr = obs    + (size_t)(b0 + c) * (T_OBS * DIN);
    const float* tgtr = target + (size_t)(b0 + c) * (T_FUT * DIN);
    float x5[5] = {0, 0, 0, 0, 0};
    if (q == 0) {
        #pragma unroll
        for (int j = 0; j < DIN; ++j) x5[j] = obsr[j];   // x_0
    }

    for (int t = 0; t <= T_ALL; ++t) {
        __syncthreads();
        const int p = t & 1;

        // A fragments: lane holds h[m = c][k = kt*32+q*8 .. +7]
        short8 ah[4];
        const short* ap = &Abuf[p][c][0];
        #pragma unroll
        for (int kt = 0; kt < 4; ++kt)
            ah[kt] = *reinterpret_cast<const short8*>(ap + kt * 32 + q * 8);

        // fused head on previous step's h (rollout region)
        if (wave == 0 && t >= T_OBS + 1) {
            const int s = t - (T_OBS + 1);
            f32x4 acc = {hb, hb, hb, hb};
            #pragma unroll
            for (int kt = 0; kt < 4; ++kt)
                acc = MFMA(ah[kt], Whd[kt], acc);
            if (c < DIN) {
                #pragma unroll
                for (int r = 0; r < 4; ++r) {
                    int m = q * 4 + r;
                    out[((size_t)(b0 + m) * T_FUT + s) * DIN + c] = acc[r];
                }
            }
        }
        if (t == T_ALL) break;

        if (t == T_OBS) load_phase(cWih, cWhh, cbih, cbhh);  // switch to cell

        // x fragment (5th K-tile): q==0 lanes hold x[m][0..4]
        short8 ax = (short8)0;
        if (q == 0) {
            #pragma unroll
            for (int j = 0; j < DIN; ++j) ax[j] = f2bf(x5[j]);
            const int tn = t + 1;   // prefetch next step's x
            if (tn < T_ALL) {
                const float* px = (tn < T_OBS)  ? (obsr + tn * DIN)
                                : (tn == T_OBS) ? (obsr + (T_OBS - 1) * DIN)
                                                : (tgtr + (tn - T_OBS - 1) * DIN);
                #pragma unroll
                for (int j = 0; j < DIN; ++j) x5[j] = px[j];
            }
        }

        // gate MFMAs: 15/wave/step
        f32x4 aR  = {br, br, br, br};
        f32x4 aZ  = {bz, bz, bz, bz};
        f32x4 aNh = {bnh_, bnh_, bnh_, bnh_};
        f32x4 aNi = {bni_, bni_, bni_, bni_};
        #pragma unroll
        for (int kt = 0; kt < 4; ++kt) {
            aR  = MFMA(ah[kt], Wr[kt], aR);
            aZ  = MFMA(ah[kt], Wz[kt], aZ);
            aNh = MFMA(ah[kt], Wn[kt], aNh);
        }
        aR  = MFMA(ax, Wr[4], aR);
        aZ  = MFMA(ax, Wz[4], aZ);
        aNi = MFMA(ax, Wn[4], aNi);

        // elementwise GRU update (lane-local)
        #pragma unroll
        for (int r = 0; r < 4; ++r) {
            float rv = sigm(aR[r]);
            float zv = sigm(aZ[r]);
            float nv = tanh_(aNi[r] + rv * aNh[r]);
            float hn = nv + zv * (hreg[r] - nv);   // (1-z)n + z h
            hreg[r] = hn;
            Abuf[1 - p][q * 4 + r][wbase + c] = f2bf(hn);
        }
    }
}

extern "C" void kernel_launch(void* const* d_in, const int* in_sizes, int n_in,
                              void* d_out, int out_size, void* d_ws, size_t ws_size,
                              hipStream_t stream)
{
    (void)in_sizes; (void)n_in; (void)d_ws; (void)ws_size; (void)out_size;
    gru_tracemodel_kernel<<<dim3(B_TOT / BT), dim3(512), 0, stream>>>(
        (const float*)d_in[0],  (const float*)d_in[1],
        (const float*)d_in[2],  (const float*)d_in[3],
        (const float*)d_in[4],  (const float*)d_in[5],
        (const float*)d_in[6],  (const float*)d_in[7],
        (const float*)d_in[8],  (const float*)d_in[9],
        (const float*)d_in[10], (const float*)d_in[11],
        (float*)d_out);
}

// Round 2
// 495.283 us; speedup vs baseline: 2.0594x; 2.0594x over previous
//
#include <hip/hip_runtime.h>

#define B_TOT 8192
#define T_OBS 128
#define T_FUT 64
#define T_ALL 192
#define DIN 5
#define HD 128
#define BT 16          // batch rows per block (one 16-row MFMA A-tile)
#define LDSTR 136      // LDS row stride in shorts (pad 8 to spread banks)

typedef __attribute__((ext_vector_type(8))) short short8;
typedef __attribute__((ext_vector_type(4))) float f32x4;

__device__ inline short f2bf(float f) {
    unsigned u = __float_as_uint(f);
    u += 0x7FFFu + ((u >> 16) & 1u);   // round-to-nearest-even
    return (short)(u >> 16);
}

__device__ inline float sigm(float x) {
    return __builtin_amdgcn_rcpf(1.f + __expf(-x));
}
__device__ inline float tanh_(float x) {
    return 1.f - 2.f * __builtin_amdgcn_rcpf(1.f + __expf(2.f * x));
}

__device__ inline f32x4 MFMA(short8 a, short8 b, f32x4 c) {
    return __builtin_amdgcn_mfma_f32_16x16x32_bf16(a, b, c, 0, 0, 0);
}

__device__ inline short8 load_w8(const float* p) {
    float4 a = *reinterpret_cast<const float4*>(p);
    float4 b = *reinterpret_cast<const float4*>(p + 4);
    short8 r;
    r[0] = f2bf(a.x); r[1] = f2bf(a.y); r[2] = f2bf(a.z); r[3] = f2bf(a.w);
    r[4] = f2bf(b.x); r[5] = f2bf(b.y); r[6] = f2bf(b.z); r[7] = f2bf(b.w);
    return r;
}
__device__ inline short8 load_w5(const float* p) {
    short8 r = (short8)0;
    r[0] = f2bf(p[0]); r[1] = f2bf(p[1]); r[2] = f2bf(p[2]);
    r[3] = f2bf(p[3]); r[4] = f2bf(p[4]);
    return r;
}

// 512 threads = 8 waves. Wave w owns gate-columns [16w, 16w+16) of each of
// r/z/n. Block owns 16 batch rows (one 16-row A-tile). Weights live in
// VGPRs: 15 short8 = 60 VGPRs/lane. BT=16 -> 512 blocks -> 2 blocks/CU:
// two independent recurrences per CU interleave their per-step latency
// chains (barrier, LDS round-trip, MFMA chain, transcendentals).
//
// NOTE on launch_bounds: on this toolchain the 2nd arg behaves like CUDA's
// minBlocksPerMultiprocessor. (512,2) => 16 waves/CU => VGPR cap 128 (R0
// used 120 under it). (512,4) forced a 64-VGPR cap and spilled 1.5 GB of
// scratch per dispatch (R1 regression). Keep (512,2).
__global__ __launch_bounds__(512, 2)
void gru_tracemodel_kernel(const float* __restrict__ obs, const float* __restrict__ target,
                           const float* __restrict__ eWih, const float* __restrict__ eWhh,
                           const float* __restrict__ ebih, const float* __restrict__ ebhh,
                           const float* __restrict__ cWih, const float* __restrict__ cWhh,
                           const float* __restrict__ cbih, const float* __restrict__ cbhh,
                           const float* __restrict__ headW, const float* __restrict__ headb,
                           float* __restrict__ out)
{
    __shared__ __attribute__((aligned(16))) short Abuf[2][BT][LDSTR];

    const int tid   = threadIdx.x;
    const int wave  = tid >> 6;    // 0..7
    const int lane  = tid & 63;
    const int q     = lane >> 4;   // quad (A/B k-group, C/D row-group)
    const int c     = lane & 15;   // col-in-tile / A row
    const int b0    = blockIdx.x * BT;
    const int wbase = wave * 16;   // this wave's gate-column slice

    // h0 = 0
    for (int i = tid; i < 2 * BT * LDSTR; i += 512) ((short*)Abuf)[i] = 0;

    // ---- weight fragments (B-operand: lane holds W'[n][k = kt*32+q*8+j]) ----
    // kt 0..3: Whh K-tiles; kt 4: zero-padded Wih x-tile (only q==0 nonzero)
    short8 Wr[5], Wz[5], Wn[5];
    float  br, bz, bnh_, bni_;

    auto load_phase = [&](const float* Wih, const float* Whh,
                          const float* bih, const float* bhh) {
        const int nr = 0 * HD + wbase + c;
        const int nz = 1 * HD + wbase + c;
        const int nn = 2 * HD + wbase + c;
        #pragma unroll
        for (int kt = 0; kt < 4; ++kt) {
            Wr[kt] = load_w8(Whh + nr * HD + kt * 32 + q * 8);
            Wz[kt] = load_w8(Whh + nz * HD + kt * 32 + q * 8);
            Wn[kt] = load_w8(Whh + nn * HD + kt * 32 + q * 8);
        }
        Wr[4] = (q == 0) ? load_w5(Wih + nr * DIN) : (short8)0;
        Wz[4] = (q == 0) ? load_w5(Wih + nz * DIN) : (short8)0;
        Wn[4] = (q == 0) ? load_w5(Wih + nn * DIN) : (short8)0;
        br   = bih[nr] + bhh[nr];
        bz   = bih[nz] + bhh[nz];
        bnh_ = bhh[nn];
        bni_ = bih[nn];
    };
    load_phase(eWih, eWhh, ebih, ebhh);

    // head fragments (wave 0 only): B[k][d], d = c (<5), from headW[d][k]
    short8 Whd[4];
    float  hb = 0.f;
    if (wave == 0) {
        #pragma unroll
        for (int kt = 0; kt < 4; ++kt)
            Whd[kt] = (c < DIN) ? load_w8(headW + c * HD + kt * 32 + q * 8) : (short8)0;
        hb = (c < DIN) ? headb[c] : 0.f;
    }

    // fp32 carried h: hreg[r] = h[row q*4+r][wbase+c]
    float hreg[4] = {0.f, 0.f, 0.f, 0.f};

    const float* obsr = obs    + (size_t)(b0 + c) * (T_OBS * DIN);
    const float* tgtr = target + (size_t)(b0 + c) * (T_FUT * DIN);
    float x5[5] = {0, 0, 0, 0, 0};
    if (q == 0) {
        #pragma unroll
        for (int j = 0; j < DIN; ++j) x5[j] = obsr[j];   // x_0
    }

    for (int t = 0; t <= T_ALL; ++t) {
        __syncthreads();
        const int p = t & 1;

        // A fragments: lane holds h[m = c][k = kt*32+q*8 .. +7]
        short8 ah[4];
        const short* ap = &Abuf[p][c][0];
        #pragma unroll
        for (int kt = 0; kt < 4; ++kt)
            ah[kt] = *reinterpret_cast<const short8*>(ap + kt * 32 + q * 8);

        // fused head on previous step's h (rollout region)
        if (wave == 0 && t >= T_OBS + 1) {
            const int s = t - (T_OBS + 1);
            f32x4 acc = {hb, hb, hb, hb};
            #pragma unroll
            for (int kt = 0; kt < 4; ++kt)
                acc = MFMA(ah[kt], Whd[kt], acc);
            if (c < DIN) {
                #pragma unroll
                for (int r = 0; r < 4; ++r) {
                    int m = q * 4 + r;
                    out[((size_t)(b0 + m) * T_FUT + s) * DIN + c] = acc[r];
                }
            }
        }
        if (t == T_ALL) break;

        if (t == T_OBS) load_phase(cWih, cWhh, cbih, cbhh);  // switch to cell

        // x fragment (5th K-tile): q==0 lanes hold x[m][0..4]
        short8 ax = (short8)0;
        if (q == 0) {
            #pragma unroll
            for (int j = 0; j < DIN; ++j) ax[j] = f2bf(x5[j]);
            const int tn = t + 1;   // prefetch next step's x
            if (tn < T_ALL) {
                const float* px = (tn < T_OBS)  ? (obsr + tn * DIN)
                                : (tn == T_OBS) ? (obsr + (T_OBS - 1) * DIN)
                                                : (tgtr + (tn - T_OBS - 1) * DIN);
                #pragma unroll
                for (int j = 0; j < DIN; ++j) x5[j] = px[j];
            }
        }

        // gate MFMAs: 15/wave/step
        f32x4 aR  = {br, br, br, br};
        f32x4 aZ  = {bz, bz, bz, bz};
        f32x4 aNh = {bnh_, bnh_, bnh_, bnh_};
        f32x4 aNi = {bni_, bni_, bni_, bni_};
        #pragma unroll
        for (int kt = 0; kt < 4; ++kt) {
            aR  = MFMA(ah[kt], Wr[kt], aR);
            aZ  = MFMA(ah[kt], Wz[kt], aZ);
            aNh = MFMA(ah[kt], Wn[kt], aNh);
        }
        aR  = MFMA(ax, Wr[4], aR);
        aZ  = MFMA(ax, Wz[4], aZ);
        aNi = MFMA(ax, Wn[4], aNi);

        // elementwise GRU update (lane-local)
        #pragma unroll
        for (int r = 0; r < 4; ++r) {
            float rv = sigm(aR[r]);
            float zv = sigm(aZ[r]);
            float nv = tanh_(aNi[r] + rv * aNh[r]);
            float hn = nv + zv * (hreg[r] - nv);   // (1-z)n + z h
            hreg[r] = hn;
            Abuf[1 - p][q * 4 + r][wbase + c] = f2bf(hn);
        }
    }
}

extern "C" void kernel_launch(void* const* d_in, const int* in_sizes, int n_in,
                              void* d_out, int out_size, void* d_ws, size_t ws_size,
                              hipStream_t stream)
{
    (void)in_sizes; (void)n_in; (void)d_ws; (void)ws_size; (void)out_size;
    gru_tracemodel_kernel<<<dim3(B_TOT / BT), dim3(512), 0, stream>>>(
        (const float*)d_in[0],  (const float*)d_in[1],
        (const float*)d_in[2],  (const float*)d_in[3],
        (const float*)d_in[4],  (const float*)d_in[5],
        (const float*)d_in[6],  (const float*)d_in[7],
        (const float*)d_in[8],  (const float*)d_in[9],
        (const float*)d_in[10], (const float*)d_in[11],
        (float*)d_out);
}

// Round 3
// 338.113 us; speedup vs baseline: 3.0167x; 1.4648x over previous
//
#include <hip/hip_runtime.h>

#define B_TOT 8192
#define T_OBS 128
#define T_FUT 64
#define T_ALL 192
#define DIN 5
#define HD 128
#define BT 32          // batch rows per block (two 16-row tiles)
#define LDSTR 136      // LDS row stride in shorts (pad 8 to spread banks)

#define LOG2E 1.44269504088896340736f

typedef __attribute__((ext_vector_type(8))) short short8;
typedef __attribute__((ext_vector_type(4))) float f32x4;
typedef __attribute__((ext_vector_type(2))) unsigned int u32x2;
typedef __attribute__((ext_vector_type(4))) unsigned int u32x4;

__device__ inline short f2bf(float f) {
    unsigned u = __float_as_uint(f);
    u += 0x7FFFu + ((u >> 16) & 1u);   // round-to-nearest-even
    return (short)(u >> 16);
}

// packed f32->bf16 (RNE), lo <- s0, hi <- s1
__device__ inline unsigned cvtpk(float lo, float hi) {
    unsigned r;
    asm volatile("v_cvt_pk_bf16_f32 %0, %1, %2" : "=v"(r) : "v"(lo), "v"(hi));
    return r;
}

__device__ inline f32x4 MFMA(short8 a, short8 b, f32x4 c) {
    return __builtin_amdgcn_mfma_f32_16x16x32_bf16(a, b, c, 0, 0, 0);
}

__device__ inline short8 load_w8s(const float* p, float s) {
    float4 a = *reinterpret_cast<const float4*>(p);
    float4 b = *reinterpret_cast<const float4*>(p + 4);
    short8 r;
    r[0] = f2bf(a.x * s); r[1] = f2bf(a.y * s); r[2] = f2bf(a.z * s); r[3] = f2bf(a.w * s);
    r[4] = f2bf(b.x * s); r[5] = f2bf(b.y * s); r[6] = f2bf(b.z * s); r[7] = f2bf(b.w * s);
    return r;
}
__device__ inline short8 load_w5s(const float* p, float s) {
    short8 r = (short8)0;
    r[0] = f2bf(p[0] * s); r[1] = f2bf(p[1] * s); r[2] = f2bf(p[2] * s);
    r[3] = f2bf(p[3] * s); r[4] = f2bf(p[4] * s);
    return r;
}

// 512 threads = 8 waves, 256 blocks = 1 block/CU (structural occupancy cap:
// 8 waves/CU). VALU issue is the measured limiter (R0: VALUBusy 56% +
// MfmaUtil 23% ~= 80% of wall). This version swaps MFMA operands
// (gates^T = W*h^T): A/B fragments have identical lane maps so weight/h
// fragments are unchanged, but each lane's C/D now holds 4 CONSECUTIVE
// gate-dims of one batch row -> h writeback = 2 cvt_pk + 1 ds_write_b64
// (was 4x f2bf + 4x ds_write_b16). Weights pre-scaled by log2e (2log2e for
// n-gate) so sigmoid/tanh use bare v_exp_f32 (exp2).
//
// launch_bounds(512,1): 1 block/CU structural; HW forces <=256 VGPR for
// 8-wave blocks. Do NOT request more waves via launch_bounds: (512,4)
// capped regs at 64 and spilled 1.5 GB (R1); (512,2)+BT16 still couldn't
// co-reside 2 blocks (R2, occupancy stayed 23%).
__global__ __launch_bounds__(512, 1)
void gru_tracemodel_kernel(const float* __restrict__ obs, const float* __restrict__ target,
                           const float* __restrict__ eWih, const float* __restrict__ eWhh,
                           const float* __restrict__ ebih, const float* __restrict__ ebhh,
                           const float* __restrict__ cWih, const float* __restrict__ cWhh,
                           const float* __restrict__ cbih, const float* __restrict__ cbhh,
                           const float* __restrict__ headW, const float* __restrict__ headb,
                           float* __restrict__ out)
{
    __shared__ __attribute__((aligned(16))) short Abuf[2][BT][LDSTR];

    const int tid   = threadIdx.x;
    const int wave  = tid >> 6;    // 0..7
    const int lane  = tid & 63;
    const int q     = lane >> 4;   // k-group of A/B frags; row-group of C/D
    const int c     = lane & 15;   // non-K index of A/B frags; col of C/D
    const int b0    = blockIdx.x * BT;
    const int wbase = wave * 16;   // this wave's gate-column slice

    // h0 = 0
    for (int i = tid; i < 2 * BT * LDSTR; i += 512) ((short*)Abuf)[i] = 0;

    // ---- weight fragments (A-operand now: lane holds W'[n = wbase+c][k]) ----
    // kt 0..3: Whh K-tiles; kt 4: zero-padded Wih x-tile (only q==0 nonzero)
    short8 Wr[5], Wz[5], Wn[5];
    f32x4  br4, bz4, bnh4, bni4;   // per-reg biases: n = wbase + q*4 + r

    auto load_phase = [&](const float* Wih, const float* Whh,
                          const float* bih, const float* bhh) {
        const int nr = 0 * HD + wbase + c;
        const int nz = 1 * HD + wbase + c;
        const int nn = 2 * HD + wbase + c;
        #pragma unroll
        for (int kt = 0; kt < 4; ++kt) {
            Wr[kt] = load_w8s(Whh + nr * HD + kt * 32 + q * 8, LOG2E);
            Wz[kt] = load_w8s(Whh + nz * HD + kt * 32 + q * 8, LOG2E);
            Wn[kt] = load_w8s(Whh + nn * HD + kt * 32 + q * 8, 2.f * LOG2E);
        }
        Wr[4] = (q == 0) ? load_w5s(Wih + nr * DIN, LOG2E) : (short8)0;
        Wz[4] = (q == 0) ? load_w5s(Wih + nz * DIN, LOG2E) : (short8)0;
        Wn[4] = (q == 0) ? load_w5s(Wih + nn * DIN, 2.f * LOG2E) : (short8)0;
        const int n0 = wbase + q * 4;
        #pragma unroll
        for (int r = 0; r < 4; ++r) {
            br4[r]  = (bih[0 * HD + n0 + r] + bhh[0 * HD + n0 + r]) * LOG2E;
            bz4[r]  = (bih[1 * HD + n0 + r] + bhh[1 * HD + n0 + r]) * LOG2E;
            bni4[r] = bih[2 * HD + n0 + r] * (2.f * LOG2E);
            bnh4[r] = bhh[2 * HD + n0 + r] * (2.f * LOG2E);
        }
    };
    load_phase(eWih, eWhh, ebih, ebhh);

    // head fragments (ALL waves now: head wave rotates per step).
    // A-operand: lane c holds headW[d = c][k] (unscaled), d < 5.
    short8 Whd[4];
    f32x4  hb4;
    #pragma unroll
    for (int kt = 0; kt < 4; ++kt)
        Whd[kt] = (c < DIN) ? load_w8s(headW + c * HD + kt * 32 + q * 8, 1.f) : (short8)0;
    #pragma unroll
    for (int r = 0; r < 4; ++r)
        hb4[r] = (q * 4 + r < DIN) ? headb[q * 4 + r] : 0.f;

    // fp32 carried h: hreg[a][r] = h[batch a*16+c][gate-dim wbase+q*4+r]
    float hreg[2][4] = {{0.f,0.f,0.f,0.f},{0.f,0.f,0.f,0.f}};

    const float* obsr[2] = { obs + (size_t)(b0 + c) * (T_OBS * DIN),
                             obs + (size_t)(b0 + 16 + c) * (T_OBS * DIN) };
    const float* tgtr[2] = { target + (size_t)(b0 + c) * (T_FUT * DIN),
                             target + (size_t)(b0 + 16 + c) * (T_FUT * DIN) };
    float x5[2][5] = {{0,0,0,0,0},{0,0,0,0,0}};
    if (q == 0) {
        #pragma unroll
        for (int a = 0; a < 2; ++a)
            #pragma unroll
            for (int j = 0; j < DIN; ++j) x5[a][j] = obsr[a][j];   // x_0
    }

    for (int t = 0; t <= T_ALL; ++t) {
        __syncthreads();
        const int p = t & 1;

        // h fragments (B-operand): lane holds h[batch a*16+c][k = kt*32+q*8..]
        short8 ah[2][4];
        #pragma unroll
        for (int a = 0; a < 2; ++a) {
            const short* ap = &Abuf[p][a * 16 + c][0];
            #pragma unroll
            for (int kt = 0; kt < 4; ++kt)
                ah[a][kt] = *reinterpret_cast<const short8*>(ap + kt * 32 + q * 8);
        }

        // fused head on previous step's h; wave rotates to balance skew
        if (t >= T_OBS + 1 && wave == ((t - T_OBS - 1) & 7)) {
            const int s = t - (T_OBS + 1);
            const int d0 = q * 4;
            #pragma unroll
            for (int a = 0; a < 2; ++a) {
                f32x4 acc = hb4;
                #pragma unroll
                for (int kt = 0; kt < 4; ++kt)
                    acc = MFMA(Whd[kt], ah[a][kt], acc);
                // D[d = q*4+r][batch = a*16+c]
                if (d0 < DIN) {
                    float* op = out + ((size_t)(b0 + a * 16 + c) * T_FUT + s) * DIN + d0;
                    op[0] = acc[0];
                    if (q == 0) { op[1] = acc[1]; op[2] = acc[2]; op[3] = acc[3]; }
                }
            }
        }
        if (t == T_ALL) break;

        if (t == T_OBS) load_phase(cWih, cWhh, cbih, cbhh);  // switch to cell

        // x fragment (5th K-tile, B-operand): q==0 lanes hold x[batch][0..4]
        short8 ax[2];
        {
            unsigned u0a = 0, u1a = 0, u2a = 0, u0b = 0, u1b = 0, u2b = 0;
            if (q == 0) {
                u0a = cvtpk(x5[0][0], x5[0][1]);
                u1a = cvtpk(x5[0][2], x5[0][3]);
                u2a = cvtpk(x5[0][4], 0.f);
                u0b = cvtpk(x5[1][0], x5[1][1]);
                u1b = cvtpk(x5[1][2], x5[1][3]);
                u2b = cvtpk(x5[1][4], 0.f);
            }
            u32x4 va = {u0a, u1a, u2a, 0u};
            u32x4 vb = {u0b, u1b, u2b, 0u};
            ax[0] = __builtin_bit_cast(short8, va);
            ax[1] = __builtin_bit_cast(short8, vb);
            const int tn = t + 1;   // prefetch next step's x
            if (q == 0 && tn < T_ALL) {
                #pragma unroll
                for (int a = 0; a < 2; ++a) {
                    const float* px = (tn < T_OBS)  ? (obsr[a] + tn * DIN)
                                    : (tn == T_OBS) ? (obsr[a] + (T_OBS - 1) * DIN)
                                                    : (tgtr[a] + (tn - T_OBS - 1) * DIN);
                    #pragma unroll
                    for (int j = 0; j < DIN; ++j) x5[a][j] = px[j];
                }
            }
        }

        // gate MFMAs (swapped: A = weights, B = h): 30/wave/step
        #pragma unroll
        for (int a = 0; a < 2; ++a) {
            f32x4 aR  = br4;
            f32x4 aZ  = bz4;
            f32x4 aNh = bnh4;
            f32x4 aNi = bni4;
            #pragma unroll
            for (int kt = 0; kt < 4; ++kt) {
                aR  = MFMA(Wr[kt], ah[a][kt], aR);
                aZ  = MFMA(Wz[kt], ah[a][kt], aZ);
                aNh = MFMA(Wn[kt], ah[a][kt], aNh);
            }
            aR  = MFMA(Wr[4], ax[a], aR);
            aZ  = MFMA(Wz[4], ax[a], aZ);
            aNi = MFMA(Wn[4], ax[a], aNi);

            // elementwise GRU update; accumulators are pre-scaled by log2e
            // (2log2e for n) so sigmoid/tanh use exp2 directly.
            float hn[4];
            #pragma unroll
            for (int r = 0; r < 4; ++r) {
                float rv = __builtin_amdgcn_rcpf(1.f + __builtin_amdgcn_exp2f(-aR[r]));
                float zv = __builtin_amdgcn_rcpf(1.f + __builtin_amdgcn_exp2f(-aZ[r]));
                float yv = fmaf(rv, aNh[r], aNi[r]);
                float nv = 1.f - 2.f * __builtin_amdgcn_rcpf(1.f + __builtin_amdgcn_exp2f(yv));
                float h_ = nv + zv * (hreg[a][r] - nv);   // (1-z)n + z h
                hreg[a][r] = h_;
                hn[r] = h_;
            }
            // writeback: 4 consecutive gate-dims of one row -> one b64 store
            u32x2 wv = { cvtpk(hn[0], hn[1]), cvtpk(hn[2], hn[3]) };
            *reinterpret_cast<u32x2*>(&Abuf[1 - p][a * 16 + c][wbase + q * 4]) = wv;
        }
    }
}

extern "C" void kernel_launch(void* const* d_in, const int* in_sizes, int n_in,
                              void* d_out, int out_size, void* d_ws, size_t ws_size,
                              hipStream_t stream)
{
    (void)in_sizes; (void)n_in; (void)d_ws; (void)ws_size; (void)out_size;
    gru_tracemodel_kernel<<<dim3(B_TOT / BT), dim3(512), 0, stream>>>(
        (const float*)d_in[0],  (const float*)d_in[1],
        (const float*)d_in[2],  (const float*)d_in[3],
        (const float*)d_in[4],  (const float*)d_in[5],
        (const float*)d_in[6],  (const float*)d_in[7],
        (const float*)d_in[8],  (const float*)d_in[9],
        (const float*)d_in[10], (const float*)d_in[11],
        (float*)d_out);
}